// Round 1
// baseline (38061.670 us; speedup 1.0000x reference)
//
#include <hip/hip_runtime.h>
#include <stdint.h>

#define SEQ   1024
#define BATCH 32
#define HID   512
#define G3    1536
#define NW    32          // workgroups per direction
#define JPW   16          // hidden units owned per WG
#define THREADS 384       // 6 waves: wave = (mi, g) -> 2 M-tiles x 3 gate-tiles

typedef __attribute__((ext_vector_type(8))) short  short8;
typedef __attribute__((ext_vector_type(4))) float  f32x4;
typedef __attribute__((ext_vector_type(4))) unsigned short us4;

__device__ __forceinline__ unsigned short f2bf(float f) {
  union { float f; unsigned int u; } v; v.f = f;
  unsigned int u = v.u;
  return (unsigned short)((u + 0x7FFFu + ((u >> 16) & 1u)) >> 16);
}

__device__ __forceinline__ short8 pack8(const float* __restrict__ p) {
  short8 o;
#pragma unroll
  for (int i = 0; i < 8; i++) o[i] = (short)f2bf(p[i]);
  return o;
}

__global__ void cvt_bf16(const float* __restrict__ in, unsigned short* __restrict__ out, int n4) {
  int i = blockIdx.x * blockDim.x + threadIdx.x;
  if (i >= n4) return;
  f32x4 v = ((const f32x4*)in)[i];
  us4 o;
#pragma unroll
  for (int k = 0; k < 4; k++) o[k] = f2bf(v[k]);
  ((us4*)out)[i] = o;
}

// Persistent bidirectional GRU layer. Grid = 64 WGs: dir = blockIdx>>5, wg = blockIdx&31.
// WG owns hidden units [16*wg, 16*wg+16) of its direction; steps synchronized across the
// 32 WGs of a direction via monotonic per-WG flags (agent scope) + bf16 h exchange buffer.
template<int K_IN, bool WRITE_Y>
__global__ __launch_bounds__(THREADS, 1) void gru_layer(
    const unsigned short* __restrict__ xin,   // [SEQ][BATCH][K_IN] bf16
    unsigned short* __restrict__ yout,        // [SEQ][BATCH][2*HID] bf16 (or null)
    const float* __restrict__ wih,            // [2][G3][K_IN]
    const float* __restrict__ whh,            // [2][G3][HID]
    const float* __restrict__ bih,            // [2][G3]
    const float* __restrict__ bhh,            // [2][G3]
    unsigned short* __restrict__ hbuf,        // [2][2][BATCH][HID] bf16 (dir, parity)
    int* __restrict__ flags,                  // [2][NW]
    float* __restrict__ hout)                 // [2][BATCH][HID] (this layer's slice of d_out)
{
  constexpr int KC_X = K_IN / 32;
  extern __shared__ char smem[];
  short8* wx   = (short8*)smem;                              // [3][KC_X][64] B-fragments
  float*  gbuf = (float*)(smem + (size_t)3 * KC_X * 64 * 16); // [4][BATCH][JPW]
  float*  hold = gbuf + 4 * BATCH * JPW;                      // [BATCH][JPW] fp32 state

  const int tid  = threadIdx.x;
  const int lane = tid & 63;
  const int wave = tid >> 6;
  const int mi   = wave & 1;     // batch half
  const int g    = wave >> 1;    // gate: 0=r, 1=z, 2=n
  const int quad = lane >> 4;
  const int l15  = lane & 15;

  const int dir = blockIdx.x >> 5;
  const int wg  = blockIdx.x & 31;
  const int j0  = wg * JPW;
  const bool rev = (dir == 1);

  const float* wihD = wih + (size_t)dir * G3 * K_IN;
  const float* whhD = whh + (size_t)dir * G3 * HID;

  // ---- preload x-weights into LDS as pre-swizzled MFMA B-fragments ----
  {
    const int NG = 3 * KC_X * 64;
    for (int idx = tid; idx < NG; idx += THREADS) {
      int gg  = idx / (KC_X * 64);
      int rem = idx - gg * (KC_X * 64);
      int kc  = rem >> 6;
      int ln  = rem & 63;
      int row = gg * HID + j0 + (ln & 15);
      int k0  = kc * 32 + (ln >> 4) * 8;
      wx[idx] = pack8(wihD + (size_t)row * K_IN + k0);
    }
  }
  // ---- preload h-weights into registers (B-fragments), 16 K-chunks ----
  short8 wh[16];
  {
    const float* p = whhD + (size_t)(g * HID + j0 + l15) * HID + quad * 8;
#pragma unroll
    for (int kc = 0; kc < 16; kc++) wh[kc] = pack8(p + kc * 32);
  }
  const int grow = g * HID + j0 + l15;
  const float bi   = bih[dir * G3 + grow];
  const float bh   = bhh[dir * G3 + grow];
  const float bsum = bi + bh;

  for (int idx = tid; idx < BATCH * JPW; idx += THREADS) hold[idx] = 0.f;
  __syncthreads();

  int* fl = flags + dir * NW;
  unsigned short* hb_base = hbuf + (size_t)dir * 2 * BATCH * HID;

  for (int s = 0; s < SEQ; s++) {
    const int t = rev ? (SEQ - 1 - s) : s;
    f32x4 acc, accH;
    if (g < 2) { acc = (f32x4){bsum, bsum, bsum, bsum}; accH = acc; }
    else       { acc = (f32x4){bi, bi, bi, bi}; accH = (f32x4){bh, bh, bh, bh}; }

    // ---- x-part (independent of h: overlaps the flag wait below) ----
    {
      const unsigned short* xr = xin + ((size_t)t * BATCH + (mi * 16 + l15)) * K_IN + quad * 8;
      const short8* wxp = wx + g * (KC_X * 64) + lane;
#pragma unroll 4
      for (int kc = 0; kc < KC_X; kc++) {
        short8 a = *(const short8*)(xr + kc * 32);
        acc = __builtin_amdgcn_mfma_f32_16x16x32_bf16(a, wxp[kc * 64], acc, 0, 0, 0);
      }
    }

    // ---- wait for h_{s-1} from all 32 WGs of this direction ----
    if (s > 0) {
      while (true) {
        int v = (lane < NW)
                  ? __hip_atomic_load(&fl[lane], __ATOMIC_RELAXED, __HIP_MEMORY_SCOPE_AGENT)
                  : s;
        if (__all(v >= s)) break;
        __builtin_amdgcn_s_sleep(1);
      }
      __builtin_amdgcn_fence(__ATOMIC_ACQUIRE, "agent");
      const unsigned short* hr = hb_base + (size_t)((s - 1) & 1) * BATCH * HID
                               + (size_t)(mi * 16 + l15) * HID + quad * 8;
#pragma unroll
      for (int kc = 0; kc < 16; kc++) {
        short8 a = *(const short8*)(hr + kc * 32);
        if (g < 2) acc  = __builtin_amdgcn_mfma_f32_16x16x32_bf16(a, wh[kc], acc, 0, 0, 0);
        else       accH = __builtin_amdgcn_mfma_f32_16x16x32_bf16(a, wh[kc], accH, 0, 0, 0);
      }
    }

    // ---- dump preactivations to LDS (D: row m = quad*4+r (+16*mi), col = l15) ----
#pragma unroll
    for (int r = 0; r < 4; r++) {
      int m = mi * 16 + quad * 4 + r;
      if (g < 2) gbuf[(g * BATCH + m) * JPW + l15] = acc[r];
      else {
        gbuf[(2 * BATCH + m) * JPW + l15] = acc[r];
        gbuf[(3 * BATCH + m) * JPW + l15] = accH[r];
      }
    }
    __syncthreads();

    // ---- gates + state update for owned 16 units x 32 batches ----
    for (int idx = tid; idx < BATCH * JPW; idx += THREADS) {
      int b = idx >> 4;
      int j = idx & 15;
      float pr = gbuf[(0 * BATCH + b) * JPW + j];
      float pz = gbuf[(1 * BATCH + b) * JPW + j];
      float px = gbuf[(2 * BATCH + b) * JPW + j];
      float ph = gbuf[(3 * BATCH + b) * JPW + j];
      float rr = 1.f / (1.f + __expf(-pr));
      float zz = 1.f / (1.f + __expf(-pz));
      float a2 = px + rr * ph;
      float e2 = __expf(2.f * a2);
      float nn = 1.f - 2.f / (e2 + 1.f);          // tanh(a2)
      float hp = hold[idx];
      float hnew = (1.f - zz) * nn + zz * hp;
      hold[idx] = hnew;
      unsigned short h16 = f2bf(hnew);
      hb_base[(size_t)(s & 1) * BATCH * HID + (size_t)b * HID + (j0 + j)] = h16;
      if (WRITE_Y) yout[((size_t)t * BATCH + b) * (2 * HID) + dir * HID + (j0 + j)] = h16;
      if (s == SEQ - 1) hout[((size_t)dir * BATCH + b) * HID + (j0 + j)] = hnew;
    }
    __syncthreads();

    if (tid == 0) {
      __hip_atomic_store(&fl[wg], s + 1, __ATOMIC_RELEASE, __HIP_MEMORY_SCOPE_AGENT);
    }
  }
}

extern "C" void kernel_launch(void* const* d_in, const int* in_sizes, int n_in,
                              void* d_out, int out_size, void* d_ws, size_t ws_size,
                              hipStream_t stream)
{
  const float* x       = (const float*)d_in[0];
  const float* w_ih_l0 = (const float*)d_in[1];
  const float* w_hh_l0 = (const float*)d_in[2];
  const float* b_ih_l0 = (const float*)d_in[3];
  const float* b_hh_l0 = (const float*)d_in[4];
  const float* w_ih_lr = (const float*)d_in[5];
  const float* w_hh_lr = (const float*)d_in[6];
  const float* b_ih_lr = (const float*)d_in[7];
  const float* b_hh_lr = (const float*)d_in[8];
  float* out = (float*)d_out;

  char* ws = (char*)d_ws;
  size_t off = 0;
  auto alloc = [&](size_t bytes) {
    char* p = ws + off;
    off += (bytes + 255) & ~(size_t)255;
    return p;
  };
  unsigned short* xb   = (unsigned short*)alloc((size_t)SEQ * BATCH * 256 * 2);
  unsigned short* y0   = (unsigned short*)alloc((size_t)SEQ * BATCH * 1024 * 2);
  unsigned short* y1   = (unsigned short*)alloc((size_t)SEQ * BATCH * 1024 * 2);
  unsigned short* hbuf = (unsigned short*)alloc((size_t)2 * 2 * BATCH * HID * 2);
  int*            flags = (int*)alloc(3 * 64 * sizeof(int));

  hipMemsetAsync(flags, 0, 3 * 64 * sizeof(int), stream);

  {
    int n4 = SEQ * BATCH * 256 / 4;
    cvt_bf16<<<(n4 + 255) / 256, 256, 0, stream>>>(x, xb, n4);
  }

  const int smem0 = 3 * (256 / 32)  * 64 * 16 + (4 * BATCH * JPW + BATCH * JPW) * 4;  //  34816
  const int smem1 = 3 * (1024 / 32) * 64 * 16 + (4 * BATCH * JPW + BATCH * JPW) * 4;  // 108544
  hipFuncSetAttribute(reinterpret_cast<const void*>(gru_layer<256, true>),
                      hipFuncAttributeMaxDynamicSharedMemorySize, smem0);
  hipFuncSetAttribute(reinterpret_cast<const void*>(gru_layer<1024, true>),
                      hipFuncAttributeMaxDynamicSharedMemorySize, smem1);
  hipFuncSetAttribute(reinterpret_cast<const void*>(gru_layer<1024, false>),
                      hipFuncAttributeMaxDynamicSharedMemorySize, smem1);

  gru_layer<256, true><<<64, THREADS, smem0, stream>>>(
      xb, y0, w_ih_l0, w_hh_l0, b_ih_l0, b_hh_l0, hbuf, flags, out);

  gru_layer<1024, true><<<64, THREADS, smem1, stream>>>(
      y0, y1, w_ih_lr, w_hh_lr, b_ih_lr, b_hh_lr,
      hbuf, flags + 64, out + 2 * BATCH * HID);

  gru_layer<1024, false><<<64, THREADS, smem1, stream>>>(
      y1, nullptr,
      w_ih_lr + (size_t)2 * G3 * 1024, w_hh_lr + (size_t)2 * G3 * HID,
      b_ih_lr + 2 * G3, b_hh_lr + 2 * G3,
      hbuf, flags + 128, out + 4 * BATCH * HID);
}

// Round 2
// 37485.681 us; speedup vs baseline: 1.0154x; 1.0154x over previous
//
#include <hip/hip_runtime.h>
#include <stdint.h>

#define SEQ   1024
#define BATCH 32
#define HID   512
#define G3    1536
#define NW    32          // workgroups per direction
#define JPW   16          // hidden units owned per WG
#define THREADS 384       // 6 waves: wave = (mi, g) -> 2 M-tiles x 3 gate-tiles

typedef __attribute__((ext_vector_type(8))) short  short8;
typedef __attribute__((ext_vector_type(4))) float  f32x4;
typedef __attribute__((ext_vector_type(4))) unsigned short us4;
typedef unsigned long long ull;

__device__ __forceinline__ unsigned short f2bf(float f) {
  union { float f; unsigned int u; } v; v.f = f;
  unsigned int u = v.u;
  return (unsigned short)((u + 0x7FFFu + ((u >> 16) & 1u)) >> 16);
}

__device__ __forceinline__ short8 pack8(const float* __restrict__ p) {
  short8 o;
#pragma unroll
  for (int i = 0; i < 8; i++) o[i] = (short)f2bf(p[i]);
  return o;
}

__global__ void cvt_bf16(const float* __restrict__ in, unsigned short* __restrict__ out, int n4) {
  int i = blockIdx.x * blockDim.x + threadIdx.x;
  if (i >= n4) return;
  f32x4 v = ((const f32x4*)in)[i];
  us4 o;
#pragma unroll
  for (int k = 0; k < 4; k++) o[k] = f2bf(v[k]);
  ((us4*)out)[i] = o;
}

// Persistent bidirectional GRU layer. Grid = 64 WGs: dir = blockIdx>>5, wg = blockIdx&31.
// h exchange: relaxed agent-scope atomics (sc1, bypass L1/L2, coherent at L3) — NO
// agent-scope fences anywhere in the hot loop (those compile to whole-L2 wb/inv).
template<int K_IN, bool WRITE_Y>
__global__ __launch_bounds__(THREADS, 1) void gru_layer(
    const unsigned short* __restrict__ xin,   // [SEQ][BATCH][K_IN] bf16
    unsigned short* __restrict__ yout,        // [SEQ][BATCH][2*HID] bf16 (or null)
    const float* __restrict__ wih,            // [2][G3][K_IN]
    const float* __restrict__ whh,            // [2][G3][HID]
    const float* __restrict__ bih,            // [2][G3]
    const float* __restrict__ bhh,            // [2][G3]
    unsigned short* __restrict__ hbuf,        // [2][2][BATCH][HID] bf16 (dir, parity)
    int* __restrict__ flags,                  // [2][NW]
    float* __restrict__ hout)                 // [2][BATCH][HID] (this layer's slice of d_out)
{
  constexpr int KC_X = K_IN / 32;
  extern __shared__ char smem[];
  short8* wx   = (short8*)smem;                               // [3][KC_X][64] B-fragments
  float*  gbuf = (float*)(smem + (size_t)3 * KC_X * 64 * 16); // [4][BATCH][JPW]
  float*  hold = gbuf + 4 * BATCH * JPW;                      // [BATCH][JPW] fp32 state
  unsigned short* h16b = (unsigned short*)(hold + BATCH * JPW); // [BATCH][JPW] bf16 staging

  const int tid  = threadIdx.x;
  const int lane = tid & 63;
  const int wave = tid >> 6;
  const int mi   = wave & 1;     // batch half
  const int g    = wave >> 1;    // gate: 0=r, 1=z, 2=n
  const int quad = lane >> 4;
  const int l15  = lane & 15;

  const int dir = blockIdx.x >> 5;
  const int wg  = blockIdx.x & 31;
  const int j0  = wg * JPW;
  const bool rev = (dir == 1);

  const float* wihD = wih + (size_t)dir * G3 * K_IN;
  const float* whhD = whh + (size_t)dir * G3 * HID;

  // ---- preload x-weights into LDS as pre-swizzled MFMA B-fragments ----
  {
    const int NG = 3 * KC_X * 64;
    for (int idx = tid; idx < NG; idx += THREADS) {
      int gg  = idx / (KC_X * 64);
      int rem = idx - gg * (KC_X * 64);
      int kc  = rem >> 6;
      int ln  = rem & 63;
      int row = gg * HID + j0 + (ln & 15);
      int k0  = kc * 32 + (ln >> 4) * 8;
      wx[idx] = pack8(wihD + (size_t)row * K_IN + k0);
    }
  }
  // ---- preload h-weights into registers (B-fragments), 16 K-chunks ----
  short8 wh[16];
  {
    const float* p = whhD + (size_t)(g * HID + j0 + l15) * HID + quad * 8;
#pragma unroll
    for (int kc = 0; kc < 16; kc++) wh[kc] = pack8(p + kc * 32);
  }
  const int grow = g * HID + j0 + l15;
  const float bi   = bih[dir * G3 + grow];
  const float bh   = bhh[dir * G3 + grow];
  const float bsum = bi + bh;

  for (int idx = tid; idx < BATCH * JPW; idx += THREADS) hold[idx] = 0.f;
  __syncthreads();

  int* fl = flags + dir * NW;
  ull* hb_u = (ull*)(hbuf + (size_t)dir * 2 * BATCH * HID);   // [2][BATCH][HID/4]

  for (int s = 0; s < SEQ; s++) {
    const int t = rev ? (SEQ - 1 - s) : s;
    f32x4 acc, accH;
    if (g < 2) { acc = (f32x4){bsum, bsum, bsum, bsum}; accH = acc; }
    else       { acc = (f32x4){bi, bi, bi, bi}; accH = (f32x4){bh, bh, bh, bh}; }

    // ---- x-part (independent of h: overlaps the flag wait below) ----
    {
      const unsigned short* xr = xin + ((size_t)t * BATCH + (mi * 16 + l15)) * K_IN + quad * 8;
      const short8* wxp = wx + g * (KC_X * 64) + lane;
#pragma unroll 4
      for (int kc = 0; kc < KC_X; kc++) {
        short8 a = *(const short8*)(xr + kc * 32);
        acc = __builtin_amdgcn_mfma_f32_16x16x32_bf16(a, wxp[kc * 64], acc, 0, 0, 0);
      }
    }

    // ---- wait for h_{s-1} from all 32 WGs of this direction ----
    if (s > 0) {
      while (true) {
        int v = (lane < NW)
                  ? __hip_atomic_load(&fl[lane], __ATOMIC_RELAXED, __HIP_MEMORY_SCOPE_AGENT)
                  : s;
        if (__all(v >= s)) break;
        __builtin_amdgcn_s_sleep(1);
      }
      __builtin_amdgcn_fence(__ATOMIC_ACQUIRE, "workgroup");  // compiler barrier; no cache ops
      const ull* hr = hb_u + (size_t)((s - 1) & 1) * (BATCH * HID / 4)
                    + (size_t)(mi * 16 + l15) * (HID / 4) + quad * 2;
#pragma unroll
      for (int kc = 0; kc < 16; kc++) {
        union { ull u[2]; short8 v; } hu;
        hu.u[0] = __hip_atomic_load(hr + kc * 8 + 0, __ATOMIC_RELAXED, __HIP_MEMORY_SCOPE_AGENT);
        hu.u[1] = __hip_atomic_load(hr + kc * 8 + 1, __ATOMIC_RELAXED, __HIP_MEMORY_SCOPE_AGENT);
        if (g < 2) acc  = __builtin_amdgcn_mfma_f32_16x16x32_bf16(hu.v, wh[kc], acc, 0, 0, 0);
        else       accH = __builtin_amdgcn_mfma_f32_16x16x32_bf16(hu.v, wh[kc], accH, 0, 0, 0);
      }
    }

    // ---- dump preactivations to LDS (D: row m = quad*4+r (+16*mi), col = l15) ----
#pragma unroll
    for (int r = 0; r < 4; r++) {
      int m = mi * 16 + quad * 4 + r;
      if (g < 2) gbuf[(g * BATCH + m) * JPW + l15] = acc[r];
      else {
        gbuf[(2 * BATCH + m) * JPW + l15] = acc[r];
        gbuf[(3 * BATCH + m) * JPW + l15] = accH[r];
      }
    }
    __syncthreads();

    // ---- gates + state update for owned 16 units x 32 batches ----
    for (int idx = tid; idx < BATCH * JPW; idx += THREADS) {
      int b = idx >> 4;
      int j = idx & 15;
      float pr = gbuf[(0 * BATCH + b) * JPW + j];
      float pz = gbuf[(1 * BATCH + b) * JPW + j];
      float px = gbuf[(2 * BATCH + b) * JPW + j];
      float ph = gbuf[(3 * BATCH + b) * JPW + j];
      float rr = 1.f / (1.f + __expf(-pr));
      float zz = 1.f / (1.f + __expf(-pz));
      float a2 = px + rr * ph;
      float e2 = __expf(2.f * a2);
      float nn = 1.f - 2.f / (e2 + 1.f);          // tanh(a2)
      float hp = hold[idx];
      float hnew = (1.f - zz) * nn + zz * hp;
      hold[idx] = hnew;
      unsigned short h16 = f2bf(hnew);
      h16b[idx] = h16;
      if (WRITE_Y) yout[((size_t)t * BATCH + b) * (2 * HID) + dir * HID + (j0 + j)] = h16;
      if (s == SEQ - 1) hout[((size_t)dir * BATCH + b) * HID + (j0 + j)] = hnew;
    }
    __syncthreads();

    // ---- wave 0 publishes h (cache-bypass stores) + flag; others run ahead ----
    if (wave == 0) {
      ull v0 = ((const ull*)h16b)[lane];        // ull idx u: b=u>>2, q=u&3
      ull v1 = ((const ull*)h16b)[lane + 64];
      ull* hb_st = hb_u + (size_t)(s & 1) * (BATCH * HID / 4) + (j0 >> 2);
      int b0 = lane >> 2, b1 = (lane + 64) >> 2, q = lane & 3;
      __hip_atomic_store(hb_st + b0 * (HID / 4) + q, v0, __ATOMIC_RELAXED, __HIP_MEMORY_SCOPE_AGENT);
      __hip_atomic_store(hb_st + b1 * (HID / 4) + q, v1, __ATOMIC_RELAXED, __HIP_MEMORY_SCOPE_AGENT);
      __builtin_amdgcn_fence(__ATOMIC_RELEASE, "workgroup");  // s_waitcnt only; no cache ops
      if (tid == 0)
        __hip_atomic_store(&fl[wg], s + 1, __ATOMIC_RELAXED, __HIP_MEMORY_SCOPE_AGENT);
    }
  }
}

extern "C" void kernel_launch(void* const* d_in, const int* in_sizes, int n_in,
                              void* d_out, int out_size, void* d_ws, size_t ws_size,
                              hipStream_t stream)
{
  const float* x       = (const float*)d_in[0];
  const float* w_ih_l0 = (const float*)d_in[1];
  const float* w_hh_l0 = (const float*)d_in[2];
  const float* b_ih_l0 = (const float*)d_in[3];
  const float* b_hh_l0 = (const float*)d_in[4];
  const float* w_ih_lr = (const float*)d_in[5];
  const float* w_hh_lr = (const float*)d_in[6];
  const float* b_ih_lr = (const float*)d_in[7];
  const float* b_hh_lr = (const float*)d_in[8];
  float* out = (float*)d_out;

  char* ws = (char*)d_ws;
  size_t off = 0;
  auto alloc = [&](size_t bytes) {
    char* p = ws + off;
    off += (bytes + 255) & ~(size_t)255;
    return p;
  };
  unsigned short* xb   = (unsigned short*)alloc((size_t)SEQ * BATCH * 256 * 2);
  unsigned short* y0   = (unsigned short*)alloc((size_t)SEQ * BATCH * 1024 * 2);
  unsigned short* y1   = (unsigned short*)alloc((size_t)SEQ * BATCH * 1024 * 2);
  unsigned short* hbuf = (unsigned short*)alloc((size_t)2 * 2 * BATCH * HID * 2);
  int*            flags = (int*)alloc(3 * 64 * sizeof(int));

  hipMemsetAsync(flags, 0, 3 * 64 * sizeof(int), stream);

  {
    int n4 = SEQ * BATCH * 256 / 4;
    cvt_bf16<<<(n4 + 255) / 256, 256, 0, stream>>>(x, xb, n4);
  }

  const int smem0 = 3 * (256 / 32)  * 64 * 16 + (4 * BATCH * JPW + BATCH * JPW) * 4 + BATCH * JPW * 2;
  const int smem1 = 3 * (1024 / 32) * 64 * 16 + (4 * BATCH * JPW + BATCH * JPW) * 4 + BATCH * JPW * 2;
  hipFuncSetAttribute(reinterpret_cast<const void*>(gru_layer<256, true>),
                      hipFuncAttributeMaxDynamicSharedMemorySize, smem0);
  hipFuncSetAttribute(reinterpret_cast<const void*>(gru_layer<1024, true>),
                      hipFuncAttributeMaxDynamicSharedMemorySize, smem1);
  hipFuncSetAttribute(reinterpret_cast<const void*>(gru_layer<1024, false>),
                      hipFuncAttributeMaxDynamicSharedMemorySize, smem1);

  gru_layer<256, true><<<64, THREADS, smem0, stream>>>(
      xb, y0, w_ih_l0, w_hh_l0, b_ih_l0, b_hh_l0, hbuf, flags, out);

  gru_layer<1024, true><<<64, THREADS, smem1, stream>>>(
      y0, y1, w_ih_lr, w_hh_lr, b_ih_lr, b_hh_lr,
      hbuf, flags + 64, out + 2 * BATCH * HID);

  gru_layer<1024, false><<<64, THREADS, smem1, stream>>>(
      y1, nullptr,
      w_ih_lr + (size_t)2 * G3 * 1024, w_hh_lr + (size_t)2 * G3 * HID,
      b_ih_lr + 2 * G3, b_hh_lr + 2 * G3,
      hbuf, flags + 128, out + 4 * BATCH * HID);
}

// Round 3
// 17101.822 us; speedup vs baseline: 2.2256x; 2.1919x over previous
//
#include <hip/hip_runtime.h>
#include <stdint.h>

#define SEQ   1024
#define BATCH 32
#define HID   512
#define G3    1536
#define NW    32          // workgroups per direction
#define JPW   16          // hidden units owned per WG
#define THREADS 512       // 8 waves: waves 0..5 = (mi,g) MFMA waves; 6,7 = staging helpers

typedef __attribute__((ext_vector_type(8))) short  short8;
typedef __attribute__((ext_vector_type(4))) float  f32x4;
typedef unsigned long long ull;

__device__ __forceinline__ unsigned short f2bf(float f) {
  union { float f; unsigned int u; } v; v.f = f;
  unsigned int u = v.u;
  return (unsigned short)((u + 0x7FFFu + ((u >> 16) & 1u)) >> 16);
}

__device__ __forceinline__ short8 pack8(const float* __restrict__ p) {
  short8 o;
#pragma unroll
  for (int i = 0; i < 8; i++) o[i] = (short)f2bf(p[i]);
  return o;
}

// fp32 x [T][32][256] -> bf16 A-fragment chunks [T][2 mi][8 kc][64 lane] x 16B
__global__ void cvt_swz(const float* __restrict__ in, short8* __restrict__ out, int nc) {
  int c = blockIdx.x * blockDim.x + threadIdx.x;
  if (c >= nc) return;
  int lane = c & 63, r = c >> 6;
  int kc = r & 7, r2 = r >> 3;
  int mi = r2 & 1, t = r2 >> 1;
  int b   = mi * 16 + (lane & 15);
  int col = kc * 32 + (lane >> 4) * 8;
  out[c] = pack8(in + ((size_t)t * 32 + b) * 256 + col);
}

// Persistent bidirectional GRU layer. Grid = 64 WGs: dir = blockIdx>>5, wg = blockIdx&31.
// h exchange in fragment-ordered 16B chunks via sc0/sc1 (L1/L2-bypass) loads/stores;
// consumer stages the full 32KB h into LDS with 4x16B loads/thread (one vmcnt wait),
// then gate waves ds_read_b128 fragments. No agent-scope fences in the hot loop.
template<int KCX, bool WRITE_Y>
__global__ __launch_bounds__(THREADS, 1) void gru_layer(
    const short8* __restrict__ xin,    // [T][2][KCX][64] chunks (A-fragment order)
    short8* __restrict__ yout,         // [T][2][32][64] chunks for next layer (or null)
    const float* __restrict__ wih,     // [2][G3][KCX*32]
    const float* __restrict__ whh,     // [2][G3][HID]
    const float* __restrict__ bih,     // [2][G3]
    const float* __restrict__ bhh,     // [2][G3]
    short8* __restrict__ hbuf,         // [2 dir][2 par][2 mi][16 kc][64 lane] chunks
    int* __restrict__ flags,           // [2][NW]
    float* __restrict__ hout)          // [2][BATCH][HID] slice of d_out
{
  constexpr int K_IN = KCX * 32;
  extern __shared__ char smem[];
  short8* wx   = (short8*)smem;                 // [3][KCX][64] B-fragments
  short8* hst  = wx + 3 * KCX * 64;             // [2][16][64] staged h A-fragments
  float*  gbuf = (float*)(hst + 2 * 16 * 64);   // [4][512] preactivations
  float*  hold = gbuf + 4 * 512;                // [512] fp32 state
  unsigned short* h16b = (unsigned short*)(hold + 512); // [32][16] bf16 staging

  const int tid  = threadIdx.x;
  const int lane = tid & 63;
  const int wave = tid >> 6;
  const int mi   = wave & 1;     // batch half
  const int g    = wave >> 1;    // 0=r,1=z,2=n ; 3 = helper waves
  const int quad = lane >> 4;
  const int l15  = lane & 15;
  const bool cw  = (g < 3);

  const int dir = blockIdx.x >> 5;
  const int wg  = blockIdx.x & 31;
  const int j0  = wg * JPW;
  const bool rev = (dir == 1);

  const float* wihD = wih + (size_t)dir * G3 * K_IN;
  const float* whhD = whh + (size_t)dir * G3 * HID;

  // ---- preload x-weights into LDS as pre-swizzled MFMA B-fragments ----
  {
    const int NG = 3 * KCX * 64;
    for (int idx = tid; idx < NG; idx += THREADS) {
      int gg  = idx / (KCX * 64);
      int rem = idx - gg * (KCX * 64);
      int kc  = rem >> 6;
      int ln  = rem & 63;
      int row = gg * HID + j0 + (ln & 15);
      int k0  = kc * 32 + (ln >> 4) * 8;
      wx[idx] = pack8(wihD + (size_t)row * K_IN + k0);
    }
  }
  // ---- preload h-weights into registers (B-fragments), 16 K-chunks ----
  const int ggs = cw ? g : 0;
  short8 wh[16];
  {
    const float* p = whhD + (size_t)(ggs * HID + j0 + l15) * HID + quad * 8;
#pragma unroll
    for (int kc = 0; kc < 16; kc++) wh[kc] = pack8(p + kc * 32);
  }
  const int grow = ggs * HID + j0 + l15;
  const float bi   = bih[dir * G3 + grow];
  const float bh   = bhh[dir * G3 + grow];
  const float bsum = bi + bh;

  if (tid < 512) hold[tid] = 0.f;
  __syncthreads();

  int* fl = flags + dir * NW;
  short8* hb = hbuf + (size_t)dir * 2 * 2048;    // [2 par][2048 chunks]

  for (int s = 0; s < SEQ; s++) {
    const int t = rev ? (SEQ - 1 - s) : s;
    f32x4 acc, accH;
    if (g < 2) { acc = (f32x4){bsum, bsum, bsum, bsum}; accH = acc; }
    else       { acc = (f32x4){bi, bi, bi, bi}; accH = (f32x4){bh, bh, bh, bh}; }

    // ---- x-part (independent of h; overlaps the flag wait) ----
    if (cw) {
      const short8* xr  = xin + ((size_t)(t * 2 + mi) * KCX) * 64 + lane;
      const short8* wxp = wx + g * (KCX * 64) + lane;
#pragma unroll 4
      for (int kc = 0; kc < KCX; kc++) {
        acc = __builtin_amdgcn_mfma_f32_16x16x32_bf16(xr[kc * 64], wxp[kc * 64], acc, 0, 0, 0);
      }
    }

    if (s > 0) {
      // ---- wait for h_{s-1} from all 32 WGs of this direction ----
      while (true) {
        int v = (lane < NW)
                  ? __hip_atomic_load(&fl[lane], __ATOMIC_RELAXED, __HIP_MEMORY_SCOPE_AGENT)
                  : s;
        if (__all(v >= s)) break;
        __builtin_amdgcn_s_sleep(1);
      }
      // ---- stage full h (32KB) into LDS: 4 x 16B bypass loads per thread ----
      {
        const char* src = (const char*)hb + (size_t)((s - 1) & 1) * 32768 + (size_t)tid * 16;
        short8 c0, c1, c2, c3;
        asm volatile(
            "global_load_dwordx4 %0, %4, off sc0 sc1\n\t"
            "global_load_dwordx4 %1, %5, off sc0 sc1\n\t"
            "global_load_dwordx4 %2, %6, off sc0 sc1\n\t"
            "global_load_dwordx4 %3, %7, off sc0 sc1\n\t"
            "s_waitcnt vmcnt(0)"
            : "=v"(c0), "=v"(c1), "=v"(c2), "=v"(c3)
            : "v"(src), "v"(src + 8192), "v"(src + 16384), "v"(src + 24576)
            : "memory");
        hst[tid]        = c0;
        hst[tid + 512]  = c1;
        hst[tid + 1024] = c2;
        hst[tid + 1536] = c3;
      }
      __syncthreads();
      // ---- h-MFMA from LDS fragments ----
      if (cw) {
        const short8* hr = hst + mi * (16 * 64) + lane;
#pragma unroll
        for (int kc = 0; kc < 16; kc++) {
          short8 a = hr[kc * 64];
          if (g < 2) acc  = __builtin_amdgcn_mfma_f32_16x16x32_bf16(a, wh[kc], acc, 0, 0, 0);
          else       accH = __builtin_amdgcn_mfma_f32_16x16x32_bf16(a, wh[kc], accH, 0, 0, 0);
        }
      }
    }

    // ---- dump preactivations to LDS (D: row m = quad*4+r (+16*mi), col = l15) ----
    if (cw) {
#pragma unroll
      for (int r = 0; r < 4; r++) {
        int m = mi * 16 + quad * 4 + r;
        if (g < 2) gbuf[(g * 32 + m) * JPW + l15] = acc[r];
        else {
          gbuf[(2 * 32 + m) * JPW + l15] = acc[r];
          gbuf[(3 * 32 + m) * JPW + l15] = accH[r];
        }
      }
    }
    __syncthreads();

    // ---- gates + state update: exactly one (b,j) per thread ----
    {
      int b = tid >> 4, j = tid & 15;
      float pr = gbuf[(0 * 32 + b) * JPW + j];
      float pz = gbuf[(1 * 32 + b) * JPW + j];
      float px = gbuf[(2 * 32 + b) * JPW + j];
      float ph = gbuf[(3 * 32 + b) * JPW + j];
      float rr = 1.f / (1.f + __expf(-pr));
      float zz = 1.f / (1.f + __expf(-pz));
      float a2 = px + rr * ph;
      float e2 = __expf(2.f * a2);
      float nn = 1.f - 2.f / (e2 + 1.f);          // tanh(a2)
      float hp = hold[tid];
      float hnew = (1.f - zz) * nn + zz * hp;
      hold[tid] = hnew;
      h16b[tid] = f2bf(hnew);                     // [b][j] = b*16+j = tid
      if (s == SEQ - 1) hout[((size_t)dir * 32 + b) * HID + (j0 + j)] = hnew;
    }
    __syncthreads();

    // ---- wave 0 publishes h chunks (bypass stores) + flag; others run ahead ----
    if (wave == 0) {
      int b = lane >> 1, half = lane & 1;
      short8 v = ((short8*)h16b)[lane];           // 16B = h16b[b][half*8 .. +8]
      int q   = ((wg & 1) << 1) + half;
      int lf  = (b & 15) + (q << 4);
      int mib = b >> 4;
      size_t ci = (size_t)(s & 1) * 2048 + ((size_t)(mib * 16 + (wg >> 1)) * 64 + lf);
      asm volatile("global_store_dwordx4 %0, %1, off sc0 sc1"
                   :: "v"(hb + ci), "v"(v) : "memory");
      if (WRITE_Y) {
        int kc2 = (dir << 4) + (wg >> 1);
        yout[((size_t)(t * 2 + mib) * 32 + kc2) * 64 + lf] = v;  // plain store
      }
      asm volatile("s_waitcnt vmcnt(0)" ::: "memory");
      if (lane == 0)
        __hip_atomic_store(&fl[wg], s + 1, __ATOMIC_RELAXED, __HIP_MEMORY_SCOPE_AGENT);
    }
  }
}

extern "C" void kernel_launch(void* const* d_in, const int* in_sizes, int n_in,
                              void* d_out, int out_size, void* d_ws, size_t ws_size,
                              hipStream_t stream)
{
  const float* x       = (const float*)d_in[0];
  const float* w_ih_l0 = (const float*)d_in[1];
  const float* w_hh_l0 = (const float*)d_in[2];
  const float* b_ih_l0 = (const float*)d_in[3];
  const float* b_hh_l0 = (const float*)d_in[4];
  const float* w_ih_lr = (const float*)d_in[5];
  const float* w_hh_lr = (const float*)d_in[6];
  const float* b_ih_lr = (const float*)d_in[7];
  const float* b_hh_lr = (const float*)d_in[8];
  float* out = (float*)d_out;

  char* ws = (char*)d_ws;
  size_t off = 0;
  auto alloc = [&](size_t bytes) {
    char* p = ws + off;
    off += (bytes + 255) & ~(size_t)255;
    return p;
  };
  short8* xb   = (short8*)alloc((size_t)SEQ * 2 * 8 * 64 * 16);    // 16 MB
  short8* y0   = (short8*)alloc((size_t)SEQ * 2 * 32 * 64 * 16);   // 64 MB
  short8* y1   = (short8*)alloc((size_t)SEQ * 2 * 32 * 64 * 16);   // 64 MB
  short8* hbuf = (short8*)alloc((size_t)2 * 2 * 2048 * 16);        // 128 KB
  int*    flags = (int*)alloc(3 * 64 * sizeof(int));

  hipMemsetAsync(flags, 0, 3 * 64 * sizeof(int), stream);

  {
    int nc = SEQ * 2 * 8 * 64;
    cvt_swz<<<(nc + 255) / 256, 256, 0, stream>>>(x, xb, nc);
  }

  const int smem0 = (3 * 8  * 64 + 2 * 16 * 64) * 16 + (4 * 512 + 512) * 4 + 512 * 2;  //  68608
  const int smem1 = (3 * 32 * 64 + 2 * 16 * 64) * 16 + (4 * 512 + 512) * 4 + 512 * 2;  // 142336
  hipFuncSetAttribute(reinterpret_cast<const void*>(gru_layer<8, true>),
                      hipFuncAttributeMaxDynamicSharedMemorySize, smem0);
  hipFuncSetAttribute(reinterpret_cast<const void*>(gru_layer<32, true>),
                      hipFuncAttributeMaxDynamicSharedMemorySize, smem1);
  hipFuncSetAttribute(reinterpret_cast<const void*>(gru_layer<32, false>),
                      hipFuncAttributeMaxDynamicSharedMemorySize, smem1);

  gru_layer<8, true><<<64, THREADS, smem0, stream>>>(
      xb, y0, w_ih_l0, w_hh_l0, b_ih_l0, b_hh_l0, hbuf, flags, out);

  gru_layer<32, true><<<64, THREADS, smem1, stream>>>(
      y0, y1, w_ih_lr, w_hh_lr, b_ih_lr, b_hh_lr,
      hbuf, flags + 64, out + 2 * BATCH * HID);

  gru_layer<32, false><<<64, THREADS, smem1, stream>>>(
      y1, nullptr,
      w_ih_lr + (size_t)2 * G3 * 1024, w_hh_lr + (size_t)2 * G3 * HID,
      b_ih_lr + 2 * G3, b_hh_lr + 2 * G3,
      hbuf, flags + 128, out + 4 * BATCH * HID);
}

// Round 5
// 12269.447 us; speedup vs baseline: 3.1022x; 1.3939x over previous
//
#include <hip/hip_runtime.h>
#include <stdint.h>

#define SEQ   1024
#define BATCH 32
#define HID   512
#define G3    1536
#define NW    32          // workgroups per direction
#define JPW   16          // hidden units owned per WG
#define THREADS 384       // 6 waves: wave = (mi, g) -> 2 M-tiles x 3 gate-tiles
#define FSTR  256         // flag spacing in ints (1KB) -> distinct L3 sectors

typedef __attribute__((ext_vector_type(8))) short  short8;
typedef __attribute__((ext_vector_type(4))) float  f32x4;

__device__ __forceinline__ unsigned short f2bf(float f) {
  union { float f; unsigned int u; } v; v.f = f;
  unsigned int u = v.u;
  return (unsigned short)((u + 0x7FFFu + ((u >> 16) & 1u)) >> 16);
}

__device__ __forceinline__ short8 pack8(const float* __restrict__ p) {
  short8 o;
#pragma unroll
  for (int i = 0; i < 8; i++) o[i] = (short)f2bf(p[i]);
  return o;
}

// fp32 x [T][32][256] -> bf16 A-fragment chunks [T][2 mi][8 kc][64 lane] x 16B
__global__ void cvt_swz(const float* __restrict__ in, short8* __restrict__ out, int nc) {
  int c = blockIdx.x * blockDim.x + threadIdx.x;
  if (c >= nc) return;
  int lane = c & 63, r = c >> 6;
  int kc = r & 7, r2 = r >> 3;
  int mi = r2 & 1, t = r2 >> 1;
  int b   = mi * 16 + (lane & 15);
  int col = kc * 32 + (lane >> 4) * 8;
  out[c] = pack8(in + ((size_t)t * 32 + b) * 256 + col);
}

// Persistent bidirectional GRU layer. Grid = 64 WGs: dir = blockIdx>>5, wg = blockIdx&31.
// Exchange path: spread flags (1KB apart), wave0-only poll + barrier release, direct
// register staging of h fragments (16x16B sc0/sc1 loads, one vmcnt — outputs are
// EARLY-CLOBBER: async load results must never alias address reg pairs), direct dword
// publish from gate threads. No LDS round-trips for h, no agent fences in the loop.
template<int KCX, bool WRITE_Y>
__global__ __launch_bounds__(THREADS, 1) void gru_layer(
    const short8* __restrict__ xin,    // [T][2][KCX][64] chunks (A-fragment order)
    short8* __restrict__ yout,         // [T][2][32][64] chunks for next layer (or null)
    const float* __restrict__ wih,     // [2][G3][KCX*32]
    const float* __restrict__ whh,     // [2][G3][HID]
    const float* __restrict__ bih,     // [2][G3]
    const float* __restrict__ bhh,     // [2][G3]
    short8* __restrict__ hbuf,         // [2 dir][2 par][2 mi][16 kc][64 lane] chunks
    int* __restrict__ flags,           // [2][NW][FSTR]
    float* __restrict__ hout)          // [2][BATCH][HID] slice of d_out
{
  constexpr int K_IN = KCX * 32;
  extern __shared__ char smem[];
  short8* wx   = (short8*)smem;                 // [3][KCX][64] B-fragments
  float*  gbuf = (float*)(wx + 3 * KCX * 64);   // [4][32][16] preactivations
  float*  hold = gbuf + 4 * 512;                // [32][16] fp32 state

  const int tid  = threadIdx.x;
  const int lane = tid & 63;
  const int wave = tid >> 6;
  const int mi   = wave & 1;     // batch half
  const int g    = wave >> 1;    // gate: 0=r, 1=z, 2=n
  const int quad = lane >> 4;
  const int l15  = lane & 15;

  const int dir = blockIdx.x >> 5;
  const int wg  = blockIdx.x & 31;
  const int j0  = wg * JPW;
  const bool rev = (dir == 1);

  const float* wihD = wih + (size_t)dir * G3 * K_IN;
  const float* whhD = whh + (size_t)dir * G3 * HID;

  // ---- preload x-weights into LDS as pre-swizzled MFMA B-fragments ----
  {
    const int NG = 3 * KCX * 64;
    for (int idx = tid; idx < NG; idx += THREADS) {
      int gg  = idx / (KCX * 64);
      int rem = idx - gg * (KCX * 64);
      int kc  = rem >> 6;
      int ln  = rem & 63;
      int row = gg * HID + j0 + (ln & 15);
      int k0  = kc * 32 + (ln >> 4) * 8;
      wx[idx] = pack8(wihD + (size_t)row * K_IN + k0);
    }
  }
  // ---- preload h-weights into registers (B-fragments), 16 K-chunks ----
  short8 wh[16];
  {
    const float* p = whhD + (size_t)(g * HID + j0 + l15) * HID + quad * 8;
#pragma unroll
    for (int kc = 0; kc < 16; kc++) wh[kc] = pack8(p + kc * 32);
  }
  const int grow = g * HID + j0 + l15;
  const float bi   = bih[dir * G3 + grow];
  const float bh   = bhh[dir * G3 + grow];
  const float bsum = bi + bh;

  for (int idx = tid; idx < 512; idx += THREADS) hold[idx] = 0.f;
  __syncthreads();

  int* fl = flags + dir * NW * FSTR;
  char* hb = (char*)(hbuf + (size_t)dir * 2 * 2048);  // [2 par][32KB]

  for (int s = 0; s < SEQ; s++) {
    const int t = rev ? (SEQ - 1 - s) : s;
    f32x4 acc, accH;
    if (g < 2) acc = (f32x4){bsum, bsum, bsum, bsum};
    else       acc = (f32x4){bi, bi, bi, bi};
    accH = (f32x4){bh, bh, bh, bh};
    f32x4 xq = (f32x4){0.f, 0.f, 0.f, 0.f};

    // ---- x-part (two chains; overlaps poll/drain latency) ----
    {
      const short8* xr  = xin + ((size_t)(t * 2 + mi) * KCX) * 64 + lane;
      const short8* wxp = wx + g * (KCX * 64) + lane;
#pragma unroll
      for (int kc = 0; kc < KCX; kc += 2) {
        acc = __builtin_amdgcn_mfma_f32_16x16x32_bf16(xr[kc * 64], wxp[kc * 64], acc, 0, 0, 0);
        xq  = __builtin_amdgcn_mfma_f32_16x16x32_bf16(xr[(kc + 1) * 64], wxp[(kc + 1) * 64], xq, 0, 0, 0);
      }
    }

    f32x4 p0 = (f32x4){0.f, 0.f, 0.f, 0.f};
    f32x4 p1 = (f32x4){0.f, 0.f, 0.f, 0.f};
    if (s > 0) {
      // ---- wave0 polls spread flags; barrier releases the WG ----
      if (wave == 0) {
        while (true) {
          int v = (lane < NW)
                    ? __hip_atomic_load(&fl[lane * FSTR], __ATOMIC_RELAXED, __HIP_MEMORY_SCOPE_AGENT)
                    : s;
          if (__all(v >= s)) break;
        }
      }
      __syncthreads();
      // ---- direct register staging: 16 x 16B bypass loads, one vmcnt ----
      const char* hp = hb + (size_t)((s - 1) & 1) * 32768 + (size_t)mi * 16384 + (size_t)lane * 16;
      short8 a0, a1, a2, a3, a4, a5, a6, a7, a8, a9, a10, a11, a12, a13, a14, a15;
      asm volatile(
          "global_load_dwordx4 %0, %16, off sc0 sc1\n\t"
          "global_load_dwordx4 %1, %16, off offset:1024 sc0 sc1\n\t"
          "global_load_dwordx4 %2, %16, off offset:2048 sc0 sc1\n\t"
          "global_load_dwordx4 %3, %16, off offset:3072 sc0 sc1\n\t"
          "global_load_dwordx4 %4, %17, off sc0 sc1\n\t"
          "global_load_dwordx4 %5, %17, off offset:1024 sc0 sc1\n\t"
          "global_load_dwordx4 %6, %17, off offset:2048 sc0 sc1\n\t"
          "global_load_dwordx4 %7, %17, off offset:3072 sc0 sc1\n\t"
          "global_load_dwordx4 %8, %18, off sc0 sc1\n\t"
          "global_load_dwordx4 %9, %18, off offset:1024 sc0 sc1\n\t"
          "global_load_dwordx4 %10, %18, off offset:2048 sc0 sc1\n\t"
          "global_load_dwordx4 %11, %18, off offset:3072 sc0 sc1\n\t"
          "global_load_dwordx4 %12, %19, off sc0 sc1\n\t"
          "global_load_dwordx4 %13, %19, off offset:1024 sc0 sc1\n\t"
          "global_load_dwordx4 %14, %19, off offset:2048 sc0 sc1\n\t"
          "global_load_dwordx4 %15, %19, off offset:3072 sc0 sc1\n\t"
          "s_waitcnt vmcnt(0)"
          : "=&v"(a0), "=&v"(a1), "=&v"(a2), "=&v"(a3),
            "=&v"(a4), "=&v"(a5), "=&v"(a6), "=&v"(a7),
            "=&v"(a8), "=&v"(a9), "=&v"(a10), "=&v"(a11),
            "=&v"(a12), "=&v"(a13), "=&v"(a14), "=&v"(a15)
          : "v"(hp), "v"(hp + 4096), "v"(hp + 8192), "v"(hp + 12288)
          : "memory");
      // ---- h-MFMA, two chains ----
      p0 = __builtin_amdgcn_mfma_f32_16x16x32_bf16(a0,  wh[0],  p0, 0, 0, 0);
      p1 = __builtin_amdgcn_mfma_f32_16x16x32_bf16(a1,  wh[1],  p1, 0, 0, 0);
      p0 = __builtin_amdgcn_mfma_f32_16x16x32_bf16(a2,  wh[2],  p0, 0, 0, 0);
      p1 = __builtin_amdgcn_mfma_f32_16x16x32_bf16(a3,  wh[3],  p1, 0, 0, 0);
      p0 = __builtin_amdgcn_mfma_f32_16x16x32_bf16(a4,  wh[4],  p0, 0, 0, 0);
      p1 = __builtin_amdgcn_mfma_f32_16x16x32_bf16(a5,  wh[5],  p1, 0, 0, 0);
      p0 = __builtin_amdgcn_mfma_f32_16x16x32_bf16(a6,  wh[6],  p0, 0, 0, 0);
      p1 = __builtin_amdgcn_mfma_f32_16x16x32_bf16(a7,  wh[7],  p1, 0, 0, 0);
      p0 = __builtin_amdgcn_mfma_f32_16x16x32_bf16(a8,  wh[8],  p0, 0, 0, 0);
      p1 = __builtin_amdgcn_mfma_f32_16x16x32_bf16(a9,  wh[9],  p1, 0, 0, 0);
      p0 = __builtin_amdgcn_mfma_f32_16x16x32_bf16(a10, wh[10], p0, 0, 0, 0);
      p1 = __builtin_amdgcn_mfma_f32_16x16x32_bf16(a11, wh[11], p1, 0, 0, 0);
      p0 = __builtin_amdgcn_mfma_f32_16x16x32_bf16(a12, wh[12], p0, 0, 0, 0);
      p1 = __builtin_amdgcn_mfma_f32_16x16x32_bf16(a13, wh[13], p1, 0, 0, 0);
      p0 = __builtin_amdgcn_mfma_f32_16x16x32_bf16(a14, wh[14], p0, 0, 0, 0);
      p1 = __builtin_amdgcn_mfma_f32_16x16x32_bf16(a15, wh[15], p1, 0, 0, 0);
    }

    // ---- merge chains ----
    if (g < 2) acc = acc + xq + p0 + p1;
    else { acc = acc + xq; accH = accH + p0 + p1; }

    // ---- dump preactivations to LDS (D: row m = quad*4+r (+16*mi), col = l15) ----
#pragma unroll
    for (int r = 0; r < 4; r++) {
      int m = mi * 16 + quad * 4 + r;
      if (g < 2) gbuf[(g * 32 + m) * JPW + l15] = acc[r];
      else {
        gbuf[(2 * 32 + m) * JPW + l15] = acc[r];
        gbuf[(3 * 32 + m) * JPW + l15] = accH[r];
      }
    }
    __syncthreads();

    // ---- gates + state + DIRECT publish: threads 0..255, 2 elems each ----
    if (tid < 256) {
      int b = tid >> 3, jj = tid & 7;
      int e0 = b * 16 + 2 * jj;
      float h2[2];
#pragma unroll
      for (int e = 0; e < 2; e++) {
        int idx = e0 + e;
        int j = (idx & 15);
        float pr = gbuf[(0 * 32 + b) * JPW + j];
        float pz = gbuf[(1 * 32 + b) * JPW + j];
        float px = gbuf[(2 * 32 + b) * JPW + j];
        float ph = gbuf[(3 * 32 + b) * JPW + j];
        float rr = 1.f / (1.f + __expf(-pr));
        float zz = 1.f / (1.f + __expf(-pz));
        float a2 = px + rr * ph;
        float ex = __expf(2.f * a2);
        float nn = 1.f - 2.f / (ex + 1.f);        // tanh(a2)
        float hp = hold[idx];
        float hnew = (1.f - zz) * nn + zz * hp;
        hold[idx] = hnew;
        h2[e] = hnew;
      }
      unsigned int val = (unsigned int)f2bf(h2[0]) | ((unsigned int)f2bf(h2[1]) << 16);
      int k  = j0 + 2 * jj;
      int kc = k >> 5;
      int q  = (k >> 3) & 3;
      int l16 = (b & 15) + (q << 4);
      int mib = b >> 4;
      char* dst = hb + (size_t)(s & 1) * 32768 + (size_t)mib * 16384
                + (size_t)kc * 1024 + (size_t)l16 * 16 + (size_t)(k & 7) * 2;
      asm volatile("global_store_dword %0, %1, off sc0 sc1" :: "v"(dst), "v"(val) : "memory");
      if (WRITE_Y) {
        size_t yb = (((size_t)(t * 2 + mib) * 32 + (dir << 4) + kc) * 64 + l16) * 16 + (size_t)(k & 7) * 2;
        *(unsigned int*)((char*)yout + yb) = val;
      }
      if (s == SEQ - 1) {
        hout[((size_t)dir * 32 + b) * HID + k]     = h2[0];
        hout[((size_t)dir * 32 + b) * HID + k + 1] = h2[1];
      }
    }
    asm volatile("s_waitcnt vmcnt(0)" ::: "memory");   // per-wave drain of sc1 stores
    __syncthreads();
    if (tid == 0)
      __hip_atomic_store(&fl[wg * FSTR], s + 1, __ATOMIC_RELAXED, __HIP_MEMORY_SCOPE_AGENT);
  }
}

extern "C" void kernel_launch(void* const* d_in, const int* in_sizes, int n_in,
                              void* d_out, int out_size, void* d_ws, size_t ws_size,
                              hipStream_t stream)
{
  const float* x       = (const float*)d_in[0];
  const float* w_ih_l0 = (const float*)d_in[1];
  const float* w_hh_l0 = (const float*)d_in[2];
  const float* b_ih_l0 = (const float*)d_in[3];
  const float* b_hh_l0 = (const float*)d_in[4];
  const float* w_ih_lr = (const float*)d_in[5];
  const float* w_hh_lr = (const float*)d_in[6];
  const float* b_ih_lr = (const float*)d_in[7];
  const float* b_hh_lr = (const float*)d_in[8];
  float* out = (float*)d_out;

  char* ws = (char*)d_ws;
  size_t off = 0;
  auto alloc = [&](size_t bytes) {
    char* p = ws + off;
    off += (bytes + 255) & ~(size_t)255;
    return p;
  };
  short8* xb   = (short8*)alloc((size_t)SEQ * 2 * 8 * 64 * 16);    // 16 MB
  short8* y0   = (short8*)alloc((size_t)SEQ * 2 * 32 * 64 * 16);   // 64 MB
  short8* y1   = (short8*)alloc((size_t)SEQ * 2 * 32 * 64 * 16);   // 64 MB
  short8* hbuf = (short8*)alloc((size_t)2 * 2 * 2048 * 16);        // 128 KB
  int*    flags = (int*)alloc((size_t)3 * 2 * NW * FSTR * 4);      // 192 KB

  hipMemsetAsync(flags, 0, (size_t)3 * 2 * NW * FSTR * 4, stream);

  {
    int nc = SEQ * 2 * 8 * 64;
    cvt_swz<<<(nc + 255) / 256, 256, 0, stream>>>(x, xb, nc);
  }

  const int smem0 = 3 * 8  * 64 * 16 + (4 * 512 + 512) * 4;   //  33792
  const int smem1 = 3 * 32 * 64 * 16 + (4 * 512 + 512) * 4;   // 108544
  hipFuncSetAttribute(reinterpret_cast<const void*>(gru_layer<8, true>),
                      hipFuncAttributeMaxDynamicSharedMemorySize, smem0);
  hipFuncSetAttribute(reinterpret_cast<const void*>(gru_layer<32, true>),
                      hipFuncAttributeMaxDynamicSharedMemorySize, smem1);
  hipFuncSetAttribute(reinterpret_cast<const void*>(gru_layer<32, false>),
                      hipFuncAttributeMaxDynamicSharedMemorySize, smem1);

  gru_layer<8, true><<<64, THREADS, smem0, stream>>>(
      xb, y0, w_ih_l0, w_hh_l0, b_ih_l0, b_hh_l0, hbuf, flags, out);

  gru_layer<32, true><<<64, THREADS, smem1, stream>>>(
      y0, y1, w_ih_lr, w_hh_lr, b_ih_lr, b_hh_lr,
      hbuf, flags + 2 * NW * FSTR, out + 2 * BATCH * HID);

  gru_layer<32, false><<<64, THREADS, smem1, stream>>>(
      y1, nullptr,
      w_ih_lr + (size_t)2 * G3 * 1024, w_hh_lr + (size_t)2 * G3 * HID,
      b_ih_lr + 2 * G3, b_hh_lr + 2 * G3,
      hbuf, flags + 4 * NW * FSTR, out + 4 * BATCH * HID);
}

// Round 7
// 9947.649 us; speedup vs baseline: 3.8262x; 1.2334x over previous
//
#include <hip/hip_runtime.h>
#include <stdint.h>

#define SEQ   1024
#define BATCH 32
#define HID   512
#define G3    1536
#define NW    32          // rec workgroups per direction
#define JPW   16          // hidden units owned per rec WG
#define THREADS 384       // 6 waves
#define FSTR  256         // flag spacing in ints (1KB)
#define CSTR  64          // prodcnt spacing in ints (256B)
#define CH    16          // steps per Xi chunk
#define NCH   64          // chunks per layer (CH*NCH == SEQ)
#define NG    192         // gate-row groups of 16 (= 3072/16), ng = dir*96+g*32+wg
#define NPROD 192         // producer WGs

typedef __attribute__((ext_vector_type(8))) short  short8;
typedef __attribute__((ext_vector_type(4))) float  f32x4;
typedef __attribute__((ext_vector_type(4))) unsigned short us4;
typedef unsigned long long ull;

__device__ __forceinline__ unsigned short f2bf(float f) {
  union { float f; unsigned int u; } v; v.f = f;
  unsigned int u = v.u;
  return (unsigned short)((u + 0x7FFFu + ((u >> 16) & 1u)) >> 16);
}
__device__ __forceinline__ float bf2f(unsigned short u) {
  union { unsigned int i; float f; } v; v.i = ((unsigned int)u) << 16; return v.f;
}
__device__ __forceinline__ short8 pack8(const float* __restrict__ p) {
  short8 o;
#pragma unroll
  for (int i = 0; i < 8; i++) o[i] = (short)f2bf(p[i]);
  return o;
}

// fp32 W [3072][K] -> bf16 B-fragment chunks [ng][kc][64 lane] x 16B
__global__ void cvt_wb(const float* __restrict__ w, short8* __restrict__ out, int kcx, int nc) {
  int c = blockIdx.x * blockDim.x + threadIdx.x;
  if (c >= nc) return;
  int lane = c & 63, r = c >> 6;     // r = ng*kcx + kc
  int kc = r % kcx, ng = r / kcx;
  int n   = ng * 16 + (lane & 15);
  int col = kc * 32 + (lane >> 4) * 8;
  int K = kcx * 32;
  out[c] = pack8(w + (size_t)n * K + col);
}

// One dispatch per layer, grid=256: blocks 0..63 = recurrence (dir=blk>>5, wg=blk&31);
// blocks 64..255 = 192 producers computing Xi CH steps ahead into ping-pong Xic.
// Producers paced by rec step-flags; rec gated per chunk by a device-scope counter.
// All cross-WG data moves via sc0/sc1 (L1/L2-bypass) + vmcnt drains; no fences.
template<int KCX, bool WRITE_Y>
__global__ __launch_bounds__(THREADS, 1) void gru_mega(
    const void* __restrict__ Ain,      // KCX==8: fp32 x [T][32][256]; else short8 [T][2][KCX][64]
    short8* __restrict__ yout,         // [T][2][32][64] chunks (or null)
    const short8* __restrict__ wb,     // [NG][KCX][64] B-fragments
    const float* __restrict__ whh,     // [2][G3][HID]
    const float* __restrict__ bih,     // [3072]
    const float* __restrict__ bhh,     // [3072]
    us4* __restrict__ Xic,             // [2 slot][CH][NG][2 mi][64]
    short8* __restrict__ hbuf,         // [2 dir][2 par][2 mi][16 kc][64] chunks
    int* __restrict__ flags,           // [2][NW][FSTR]
    int* __restrict__ prodcnt,         // [NCH][CSTR]
    float* __restrict__ hout)          // [2][BATCH][HID] slice of d_out
{
  __shared__ float gbuf[4 * 512];      // [4][32][16] preactivations
  __shared__ float hold[512];          // [32][16] fp32 state

  const int tid  = threadIdx.x;
  const int lane = tid & 63;
  const int wave = tid >> 6;
  const int quad = lane >> 4;
  const int l15  = lane & 15;

  if (blockIdx.x >= 64) {
    // ================= producer =================
    const int p    = blockIdx.x - 64;  // 0..191
    const int tg   = p & 15;           // sl within chunk (CH==16)
    const int ngg  = p >> 4;           // 0..11 -> ng range [ngg*16, ngg*16+16)
    const int dirp = (ngg >= 6) ? 1 : 0;
    int* fl = flags + dirp * NW * FSTR;

    for (int c = 0; c < NCH; c++) {
      const int tgt = (c >= 2) ? CH * (c - 1) : 0;   // slot free when dirp rec flags >= tgt
      if (wave == 0) {
        while (true) {
          int v = (lane < NW)
                    ? __hip_atomic_load(&fl[lane * FSTR], __ATOMIC_RELAXED, __HIP_MEMORY_SCOPE_AGENT)
                    : tgt;
          if (__all(v >= tgt)) break;
          __builtin_amdgcn_s_sleep(4);
        }
      }
      __syncthreads();
      const int sl = tg;
      const int s  = c * CH + sl;
      const int t  = dirp ? (SEQ - 1 - s) : s;
      for (int mi = 0; mi < 2; mi++) {
        short8 a[KCX];
        if constexpr (KCX == 8) {
          const float* xr = (const float*)Ain + ((size_t)t * 32 + mi * 16 + l15) * 256 + quad * 8;
#pragma unroll
          for (int kc = 0; kc < KCX; kc++) a[kc] = pack8(xr + kc * 32);
        } else {
          const short8* ap = (const short8*)Ain + ((size_t)(t * 2 + mi) * KCX) * 64 + lane;
#pragma unroll
          for (int kc = 0; kc < KCX; kc++) a[kc] = ap[kc * 64];
        }
        for (int ng = ngg * 16 + wave; ng < ngg * 16 + 16; ng += 6) {
          const short8* bp = wb + (size_t)ng * KCX * 64 + lane;
          f32x4 ac0 = (f32x4){0.f, 0.f, 0.f, 0.f};
          f32x4 ac1 = (f32x4){0.f, 0.f, 0.f, 0.f};
#pragma unroll
          for (int kc = 0; kc < KCX; kc += 2) {
            ac0 = __builtin_amdgcn_mfma_f32_16x16x32_bf16(a[kc],     bp[kc * 64],       ac0, 0, 0, 0);
            ac1 = __builtin_amdgcn_mfma_f32_16x16x32_bf16(a[kc + 1], bp[(kc + 1) * 64], ac1, 0, 0, 0);
          }
          const int n  = ng * 16 + l15;
          const int gg = (ng % 96) >> 5;                    // 0=r,1=z,2=n
          const float bias = bih[n] + (gg < 2 ? bhh[n] : 0.f);
          us4 o;
#pragma unroll
          for (int r = 0; r < 4; r++) o[r] = f2bf(ac0[r] + ac1[r] + bias);
          us4* dst = Xic + ((((size_t)(c & 1)) * CH + sl) * NG + ng) * 128 + mi * 64 + lane;
          asm volatile("global_store_dwordx2 %0, %1, off sc0 sc1" :: "v"(dst), "v"(o) : "memory");
        }
      }
      asm volatile("s_waitcnt vmcnt(0)" ::: "memory");
      __syncthreads();
      if (tid == 0)
        __hip_atomic_fetch_add(&prodcnt[c * CSTR], 1, __ATOMIC_RELAXED, __HIP_MEMORY_SCOPE_AGENT);
    }
    return;
  }

  // ================= recurrence =================
  const int mi  = wave & 1;
  const int g   = wave >> 1;
  const int dir = blockIdx.x >> 5;
  const int wg  = blockIdx.x & 31;
  const int j0  = wg * JPW;
  const bool rev = (dir == 1);
  const int ngR = dir * 96 + g * 32 + wg;

  short8 wh[16];
  {
    const float* pw = whh + (size_t)dir * G3 * HID + (size_t)(g * HID + j0 + l15) * HID + quad * 8;
#pragma unroll
    for (int kc = 0; kc < 16; kc++) wh[kc] = pack8(pw + kc * 32);
  }
  const float bh = bhh[dir * G3 + g * HID + j0 + l15];

  for (int idx = tid; idx < 512; idx += THREADS) hold[idx] = 0.f;
  __syncthreads();

  int* fl = flags + dir * NW * FSTR;
  char* hb = (char*)(hbuf + (size_t)dir * 2 * 2048);   // [2 par][32KB]

  for (int s = 0; s < SEQ; s++) {
    const int t  = rev ? (SEQ - 1 - s) : s;
    const int c  = s >> 4;
    const int sl = s & 15;

    if (wave == 0) {
      while (true) {
        int v = (s > 0 && lane < NW)
                  ? __hip_atomic_load(&fl[lane * FSTR], __ATOMIC_RELAXED, __HIP_MEMORY_SCOPE_AGENT)
                  : s;
        bool ok = __all(v >= s);
        if (ok && sl == 0) {
          int cnt = __hip_atomic_load(&prodcnt[c * CSTR], __ATOMIC_RELAXED, __HIP_MEMORY_SCOPE_AGENT);
          ok = (cnt >= NPROD);
        }
        if (ok) break;
        __builtin_amdgcn_s_sleep(1);
      }
    }
    __syncthreads();

    const char* xp = (const char*)Xic
        + (((((size_t)(c & 1)) * CH + sl) * NG + ngR) * 128 + mi * 64 + lane) * 8;
    ull xi64;
    f32x4 p0 = (f32x4){0.f, 0.f, 0.f, 0.f};
    f32x4 p1 = (f32x4){0.f, 0.f, 0.f, 0.f};

    if (s > 0) {
      const char* hp = hb + (size_t)((s - 1) & 1) * 32768 + (size_t)mi * 16384 + (size_t)lane * 16;
      short8 a0, a1, a2, a3, a4, a5, a6, a7, a8, a9, a10, a11, a12, a13, a14, a15;
      asm volatile(
          "global_load_dwordx2 %16, %21, off sc0 sc1\n\t"
          "global_load_dwordx4 %0, %17, off sc0 sc1\n\t"
          "global_load_dwordx4 %1, %17, off offset:1024 sc0 sc1\n\t"
          "global_load_dwordx4 %2, %17, off offset:2048 sc0 sc1\n\t"
          "global_load_dwordx4 %3, %17, off offset:3072 sc0 sc1\n\t"
          "global_load_dwordx4 %4, %18, off sc0 sc1\n\t"
          "global_load_dwordx4 %5, %18, off offset:1024 sc0 sc1\n\t"
          "global_load_dwordx4 %6, %18, off offset:2048 sc0 sc1\n\t"
          "global_load_dwordx4 %7, %18, off offset:3072 sc0 sc1\n\t"
          "global_load_dwordx4 %8, %19, off sc0 sc1\n\t"
          "global_load_dwordx4 %9, %19, off offset:1024 sc0 sc1\n\t"
          "global_load_dwordx4 %10, %19, off offset:2048 sc0 sc1\n\t"
          "global_load_dwordx4 %11, %19, off offset:3072 sc0 sc1\n\t"
          "global_load_dwordx4 %12, %20, off sc0 sc1\n\t"
          "global_load_dwordx4 %13, %20, off offset:1024 sc0 sc1\n\t"
          "global_load_dwordx4 %14, %20, off offset:2048 sc0 sc1\n\t"
          "global_load_dwordx4 %15, %20, off offset:3072 sc0 sc1\n\t"
          "s_waitcnt vmcnt(0)"
          : "=&v"(a0), "=&v"(a1), "=&v"(a2), "=&v"(a3),
            "=&v"(a4), "=&v"(a5), "=&v"(a6), "=&v"(a7),
            "=&v"(a8), "=&v"(a9), "=&v"(a10), "=&v"(a11),
            "=&v"(a12), "=&v"(a13), "=&v"(a14), "=&v"(a15), "=&v"(xi64)
          : "v"(hp), "v"(hp + 4096), "v"(hp + 8192), "v"(hp + 12288), "v"(xp)
          : "memory");
      p0 = __builtin_amdgcn_mfma_f32_16x16x32_bf16(a0,  wh[0],  p0, 0, 0, 0);
      p1 = __builtin_amdgcn_mfma_f32_16x16x32_bf16(a1,  wh[1],  p1, 0, 0, 0);
      p0 = __builtin_amdgcn_mfma_f32_16x16x32_bf16(a2,  wh[2],  p0, 0, 0, 0);
      p1 = __builtin_amdgcn_mfma_f32_16x16x32_bf16(a3,  wh[3],  p1, 0, 0, 0);
      p0 = __builtin_amdgcn_mfma_f32_16x16x32_bf16(a4,  wh[4],  p0, 0, 0, 0);
      p1 = __builtin_amdgcn_mfma_f32_16x16x32_bf16(a5,  wh[5],  p1, 0, 0, 0);
      p0 = __builtin_amdgcn_mfma_f32_16x16x32_bf16(a6,  wh[6],  p0, 0, 0, 0);
      p1 = __builtin_amdgcn_mfma_f32_16x16x32_bf16(a7,  wh[7],  p1, 0, 0, 0);
      p0 = __builtin_amdgcn_mfma_f32_16x16x32_bf16(a8,  wh[8],  p0, 0, 0, 0);
      p1 = __builtin_amdgcn_mfma_f32_16x16x32_bf16(a9,  wh[9],  p1, 0, 0, 0);
      p0 = __builtin_amdgcn_mfma_f32_16x16x32_bf16(a10, wh[10], p0, 0, 0, 0);
      p1 = __builtin_amdgcn_mfma_f32_16x16x32_bf16(a11, wh[11], p1, 0, 0, 0);
      p0 = __builtin_amdgcn_mfma_f32_16x16x32_bf16(a12, wh[12], p0, 0, 0, 0);
      p1 = __builtin_amdgcn_mfma_f32_16x16x32_bf16(a13, wh[13], p1, 0, 0, 0);
      p0 = __builtin_amdgcn_mfma_f32_16x16x32_bf16(a14, wh[14], p0, 0, 0, 0);
      p1 = __builtin_amdgcn_mfma_f32_16x16x32_bf16(a15, wh[15], p1, 0, 0, 0);
    } else {
      asm volatile("global_load_dwordx2 %0, %1, off sc0 sc1\n\ts_waitcnt vmcnt(0)"
                   : "=&v"(xi64) : "v"(xp) : "memory");
    }

    // ---- merge Xi + h-projection; dump preactivations (D: m = mi*16+quad*4+r) ----
#pragma unroll
    for (int r = 0; r < 4; r++) {
      int m = mi * 16 + quad * 4 + r;
      float xv = bf2f((unsigned short)(xi64 >> (16 * r)));
      if (g < 2) {
        gbuf[(g * 32 + m) * JPW + l15] = xv + p0[r] + p1[r];
      } else {
        gbuf[(2 * 32 + m) * JPW + l15] = xv;
        gbuf[(3 * 32 + m) * JPW + l15] = bh + p0[r] + p1[r];
      }
    }
    __syncthreads();

    // ---- gates + state + direct publish: threads 0..255, 2 elems each ----
    if (tid < 256) {
      int b = tid >> 3, jj = tid & 7;
      int e0 = b * 16 + 2 * jj;
      float h2[2];
#pragma unroll
      for (int e = 0; e < 2; e++) {
        int idx = e0 + e;
        int j = (idx & 15);
        float pr = gbuf[(0 * 32 + b) * JPW + j];
        float pz = gbuf[(1 * 32 + b) * JPW + j];
        float px = gbuf[(2 * 32 + b) * JPW + j];
        float ph = gbuf[(3 * 32 + b) * JPW + j];
        float rr = 1.f / (1.f + __expf(-pr));
        float zz = 1.f / (1.f + __expf(-pz));
        float a2 = px + rr * ph;
        float ex = __expf(2.f * a2);
        float nn = 1.f - 2.f / (ex + 1.f);        // tanh(a2)
        float hp2 = hold[idx];
        float hnew = (1.f - zz) * nn + zz * hp2;
        hold[idx] = hnew;
        h2[e] = hnew;
      }
      unsigned int val = (unsigned int)f2bf(h2[0]) | ((unsigned int)f2bf(h2[1]) << 16);
      int k  = j0 + 2 * jj;
      int kc = k >> 5;
      int q  = (k >> 3) & 3;
      int l16 = (b & 15) + (q << 4);
      int mib = b >> 4;
      char* dst = hb + (size_t)(s & 1) * 32768 + (size_t)mib * 16384
                + (size_t)kc * 1024 + (size_t)l16 * 16 + (size_t)(k & 7) * 2;
      asm volatile("global_store_dword %0, %1, off sc0 sc1" :: "v"(dst), "v"(val) : "memory");
      if (WRITE_Y) {
        size_t yb = (((size_t)(t * 2 + mib) * 32 + (dir << 4) + kc) * 64 + l16) * 16 + (size_t)(k & 7) * 2;
        *(unsigned int*)((char*)yout + yb) = val;
      }
      if (s == SEQ - 1) {
        hout[((size_t)dir * 32 + b) * HID + k]     = h2[0];
        hout[((size_t)dir * 32 + b) * HID + k + 1] = h2[1];
      }
    }
    asm volatile("s_waitcnt vmcnt(0)" ::: "memory");   // drain sc1 publish stores
    __syncthreads();
    if (tid == 0)
      __hip_atomic_store(&fl[wg * FSTR], s + 1, __ATOMIC_RELAXED, __HIP_MEMORY_SCOPE_AGENT);
  }
}

extern "C" void kernel_launch(void* const* d_in, const int* in_sizes, int n_in,
                              void* d_out, int out_size, void* d_ws, size_t ws_size,
                              hipStream_t stream)
{
  const float* x       = (const float*)d_in[0];
  const float* w_ih_l0 = (const float*)d_in[1];
  const float* w_hh_l0 = (const float*)d_in[2];
  const float* b_ih_l0 = (const float*)d_in[3];
  const float* b_hh_l0 = (const float*)d_in[4];
  const float* w_ih_lr = (const float*)d_in[5];
  const float* w_hh_lr = (const float*)d_in[6];
  const float* b_ih_lr = (const float*)d_in[7];
  const float* b_hh_lr = (const float*)d_in[8];
  float* out = (float*)d_out;

  char* ws = (char*)d_ws;
  size_t off = 0;
  auto alloc = [&](size_t bytes) {
    char* p = ws + off;
    off += (bytes + 255) & ~(size_t)255;
    return p;
  };
  short8* y0   = (short8*)alloc((size_t)SEQ * 2 * 32 * 64 * 16);   // 64 MB
  short8* y1   = (short8*)alloc((size_t)SEQ * 2 * 32 * 64 * 16);   // 64 MB
  short8* wb   = (short8*)alloc((size_t)NG * 32 * 64 * 16);        // 6 MB
  short8* hbuf = (short8*)alloc((size_t)2 * 2 * 2048 * 16);        // 128 KB
  int*    flags   = (int*)alloc((size_t)3 * 2 * NW * FSTR * 4);    // 192 KB
  int*    prodcnt = (int*)alloc((size_t)3 * NCH * CSTR * 4);       // 48 KB
  us4*    Xic  = (us4*)alloc((size_t)2 * CH * NG * 2 * 64 * 8);    // 6 MB
  // total ~140.4 MiB < proven-safe 151 MB (round 3)

  hipMemsetAsync(flags, 0, (size_t)3 * 2 * NW * FSTR * 4, stream);
  hipMemsetAsync(prodcnt, 0, (size_t)3 * NCH * CSTR * 4, stream);

  // ---- layer 0 (K=256, fp32 x read directly by producers) ----
  {
    int nc = NG * 8 * 64;
    cvt_wb<<<(nc + 255) / 256, 256, 0, stream>>>(w_ih_l0, wb, 8, nc);
    gru_mega<8, true><<<256, THREADS, 0, stream>>>(
        x, y0, wb, w_hh_l0, b_ih_l0, b_hh_l0, Xic, hbuf, flags, prodcnt, out);
  }
  // ---- layer 1 ----
  {
    int nc = NG * 32 * 64;
    cvt_wb<<<(nc + 255) / 256, 256, 0, stream>>>(w_ih_lr, wb, 32, nc);
    gru_mega<32, true><<<256, THREADS, 0, stream>>>(
        y0, y1, wb, w_hh_lr, b_ih_lr, b_hh_lr, Xic, hbuf,
        flags + 2 * NW * FSTR, prodcnt + NCH * CSTR, out + 2 * BATCH * HID);
  }
  // ---- layer 2 ----
  {
    int nc = NG * 32 * 64;
    cvt_wb<<<(nc + 255) / 256, 256, 0, stream>>>(w_ih_lr + (size_t)2 * G3 * 1024, wb, 32, nc);
    gru_mega<32, false><<<256, THREADS, 0, stream>>>(
        y1, nullptr, wb, w_hh_lr + (size_t)2 * G3 * HID,
        b_ih_lr + 2 * G3, b_hh_lr + 2 * G3, Xic, hbuf,
        flags + 4 * NW * FSTR, prodcnt + 2 * NCH * CSTR, out + 4 * BATCH * HID);
  }
}